// Round 10
// baseline (98.716 us; speedup 1.0000x reference)
//
#include <hip/hip_runtime.h>

#define NN 2048
#define DD 64
#define BB 64
#define PP 16384
#define TT 262144
#define EPSF 1e-6f
#define SS ((size_t)NN * DD)  // floats between consecutive bins of v (bin-major)

// ---------------- ws layout (bytes) ----------------
// 0     : double acc
// 1024  : int cnt[2048]     (node-i histogram)
// 9216  : int cursor[2048]
// 17408 : int perm[PP]      (pair ids sorted by node i)
// 82944 : float bounds[65]
// 83456 : float widths[64]
// 83968 : float innerPad[64]
// 84480 : float4 table[PP*BB]  (n2_left, d0, qq, bsum) = 16.78 MB

typedef unsigned uv2 __attribute__((ext_vector_type(2)));

template <int CTRL, int RM = 0xF, bool BC = true>
__device__ __forceinline__ float dpp_add(float x) {
    int y = __builtin_amdgcn_update_dpp(0, __float_as_int(x), CTRL, RM, 0xF, BC);
    return x + __int_as_float(y);
}

template <int PAT>
__device__ __forceinline__ float swz_add(float x) {
    return x + __int_as_float(__builtin_amdgcn_ds_swizzle(__float_as_int(x), PAT));
}

// xor16 / xor32 adds on the VALU pipe (permlane swaps), LDS fallback if absent
__device__ __forceinline__ float xor16_add(float x) {
#if __has_builtin(__builtin_amdgcn_permlane16_swap)
    uv2 r = __builtin_amdgcn_permlane16_swap(__float_as_uint(x), __float_as_uint(x),
                                             false, false);
    return __uint_as_float(r.x) + __uint_as_float(r.y);
#else
    return swz_add<0x401F>(x);
#endif
}
__device__ __forceinline__ float xor32_add(float x) {
#if __has_builtin(__builtin_amdgcn_permlane32_swap)
    uv2 r = __builtin_amdgcn_permlane32_swap(__float_as_uint(x), __float_as_uint(x),
                                             false, false);
    return __uint_as_float(r.x) + __uint_as_float(r.y);
#else
    return x + __shfl_xor(x, 32, 64);
#endif
}

// full 64-lane sum, result on all lanes
__device__ __forceinline__ float reduce1(float a) {
    a = dpp_add<0xB1>(a);     // quad_perm xor1
    a = dpp_add<0x4E>(a);     // quad_perm xor2
    a = dpp_add<0x141>(a);    // row_half_mirror (completes sum of 8)
    a = swz_add<0x201F>(a);   // xor8
    a = xor16_add(a);
    a = xor32_add(a);
    return a;
}

// 64-lane inclusive prefix sum (canonical 6-DPP scan)
__device__ __forceinline__ float incl_scan(float x) {
    x = dpp_add<0x111>(x);             // row_shr:1
    x = dpp_add<0x112>(x);             // row_shr:2
    x = dpp_add<0x114>(x);             // row_shr:4
    x = dpp_add<0x118>(x);             // row_shr:8
    x = dpp_add<0x142, 0xA, false>(x); // row_bcast:15 -> rows 1,3
    x = dpp_add<0x143, 0xC, false>(x); // row_bcast:31 -> rows 2,3
    return x;
}

__global__ void k_bounds(const float* __restrict__ brw, float* __restrict__ bounds,
                         float* __restrict__ widths, float* __restrict__ innerPad,
                         int* __restrict__ cnt, double* __restrict__ acc) {
    if (blockIdx.x != 0) {
        // blocks 1..8: zero cnt[2048] and acc (absorbs the old memset dispatch)
        int t = (blockIdx.x - 1) * 64 + threadIdx.x;  // 0..511
#pragma unroll
        for (int k = 0; k < 4; k++) cnt[t * 4 + k] = 0;
        if (blockIdx.x == 1 && threadIdx.x == 0) acc[0] = 0.0;
        return;
    }
    int lane = threadIdx.x;  // 64 threads
    float w = brw[lane];
    float m = w;
#pragma unroll
    for (int s = 32; s >= 1; s >>= 1) m = fmaxf(m, __shfl_xor(m, s, 64));
    float e = expf(w - m);
    float tot = e;
#pragma unroll
    for (int s = 32; s >= 1; s >>= 1) tot += __shfl_xor(tot, s, 64);
    float sm = e / tot;
    float c = sm;  // inclusive prefix sum
#pragma unroll
    for (int off = 1; off < 64; off <<= 1) {
        float t = __shfl_up(c, off, 64);
        if (lane >= off) c += t;
    }
    float cexcl = __shfl_up(c, 1, 64);
    if (lane == 0) cexcl = 0.f;
    if (lane == 0) bounds[0] = 0.f;
    bounds[lane + 1] = c;
    widths[lane] = c - cexcl;
    innerPad[lane] = (lane == 63) ? 3.4e38f : c;  // inner = bounds[1..63]
}

__global__ void k_hist2(const int* __restrict__ pairs, int* __restrict__ cnt) {
    int t = blockIdx.x * 256 + threadIdx.x;  // t < PP; pairs[t] = node i
    atomicAdd(&cnt[pairs[t]], 1);
}

__global__ __launch_bounds__(1024) void k_scan2(const int* __restrict__ cnt,
                                                int* __restrict__ cursor) {
    __shared__ int waveTot[16];
    __shared__ int waveOff[16];
    int tid = threadIdx.x;  // 1024 threads, 2 entries each
    int a = cnt[tid * 2], b = cnt[tid * 2 + 1];
    int s = a + b;
    int lane = tid & 63, wid = tid >> 6;
    int incl = s;
#pragma unroll
    for (int off = 1; off < 64; off <<= 1) {
        int t2 = __shfl_up(incl, off, 64);
        if (lane >= off) incl += t2;
    }
    if (lane == 63) waveTot[wid] = incl;
    __syncthreads();
    if (tid == 0) {
        int r = 0;
        for (int w = 0; w < 16; w++) { waveOff[w] = r; r += waveTot[w]; }
    }
    __syncthreads();
    int run = waveOff[wid] + (incl - s);  // exclusive prefix for this thread
    cursor[tid * 2] = run;
    cursor[tid * 2 + 1] = run + a;
}

__global__ void k_scatter2(const int* __restrict__ pairs, int* __restrict__ cursor,
                           int* __restrict__ perm) {
    int t = blockIdx.x * 256 + threadIdx.x;
    int pos = atomicAdd(&cursor[pairs[t]], 1);
    perm[pos] = t;
}

__global__ __launch_bounds__(256) void k_pairs(
    const float* __restrict__ x0, const float* __restrict__ v,
    const float* __restrict__ beta, const int* __restrict__ pairs,
    const int* __restrict__ perm, const float* __restrict__ widths,
    float4* __restrict__ table, double* __restrict__ acc_out) {
    __shared__ float tile[4][8][68];  // per-wave bounce tile (blocked -> lane=dim)
    __shared__ double bacc[4];
    const int wid = threadIdx.x >> 6;
    const int lane = threadIdx.x & 63;
    const int bid = blockIdx.x;
    const int vb = ((bid & 7) << 9) | (bid >> 3);  // XCD-contiguous p-ranges (4096 blocks)
    const int p = perm[vb * 4 + wid];

    const int i = pairs[p];
    const int j = pairs[PP + p];
    const float bsum = beta[i] + beta[j];

    float dx0 = x0[i * DD + lane] - x0[j * DD + lane];
    float xt = dx0;
    float n2_0 = reduce1(dx0 * dx0);
    float rr0 = __builtin_amdgcn_sqrtf(n2_0);
    float numer0 = rr0 * __expf(bsum - rr0);

    // blocked dwordx4 gather: inst (c,m) -> lane covers row 8c+4m+(lane>>4),
    // dims 4*(lane&15)..+3 (row = 256B contiguous in v's [b][n][d] layout)
    const float4* __restrict__ v4 = (const float4*)v;
    const unsigned laneoff = (unsigned)((lane >> 4) * (SS / 4) + (lane & 15));
    const unsigned vbi = (unsigned)i * (DD / 4) + laneoff;
    const unsigned vbj = (unsigned)j * (DD / 4) + laneoff;
    const unsigned ROW4 = (unsigned)(SS / 4);  // 32768 float4s between rows

    float4 cA0 = v4[vbi];
    float4 cA1 = v4[vbi + 4u * ROW4];
    float4 cB0 = v4[vbj];
    float4 cB1 = v4[vbj + 4u * ROW4];

    float (*T)[68] = tile[wid];
    const int wrow = lane >> 4;          // 0..3 (row within 4-row group)
    const int wcol = (lane & 15) * 4;    // dim quad start
    const int cls = lane & 7;            // class-select id
    const int grp = lane >> 3;           // chunk-gate id

    float d0r = 0.f, qqr = 0.f;  // lane b ends holding bin b's reduced d0, qq

#pragma unroll
    for (int c = 0; c < 8; c++) {
        float4 nA0, nA1, nB0, nB1;
        if (c < 7) {  // 1-chunk-ahead prefetch (4 dwordx4 insts, 2 per side)
            unsigned o = (unsigned)(8 * (c + 1)) * ROW4;
            nA0 = v4[vbi + o];
            nA1 = v4[vbi + o + 4u * ROW4];
            nB0 = v4[vbj + o];
            nB1 = v4[vbj + o + 4u * ROW4];
        }
        // dv in blocked layout -> LDS (b128 writes, uniform bank depth)
        float4 dv0, dv1;
        dv0.x = cA0.x - cB0.x; dv0.y = cA0.y - cB0.y;
        dv0.z = cA0.z - cB0.z; dv0.w = cA0.w - cB0.w;
        dv1.x = cA1.x - cB1.x; dv1.y = cA1.y - cB1.y;
        dv1.z = cA1.z - cB1.z; dv1.w = cA1.w - cB1.w;
        *(float4*)&T[wrow][wcol] = dv0;        // rows 0..3 of chunk
        *(float4*)&T[4 + wrow][wcol] = dv1;    // rows 4..7 of chunk

        // lane=dim sweep over the 8 bins (same-wave DS ordering: reads see writes)
        float zd = 0.f, zq = 0.f;
#pragma unroll
        for (int b = 0; b < 8; b++) {
            float dv = T[b][lane];
            float d0p = xt * dv;
            float qqp = dv * dv;
            d0p = dpp_add<0xB1>(d0p);  qqp = dpp_add<0xB1>(qqp);   // xor1
            d0p = dpp_add<0x4E>(d0p);  qqp = dpp_add<0x4E>(qqp);   // xor2
            d0p = dpp_add<0x141>(d0p); qqp = dpp_add<0x141>(qqp);  // half-mirror
            if (cls == b) { zd = d0p; zq = qqp; }  // stash bin b's 8-partials
            xt = fmaf(dv, widths[c * 8 + b], xt);  // widths: scalar load
        }
        // cross-class finish for all 8 bins at once
        zd = swz_add<0x201F>(zd);  zq = swz_add<0x201F>(zq);  // xor8
        zd = xor16_add(zd);        zq = xor16_add(zq);
        zd = xor32_add(zd);        zq = xor32_add(zq);
        if (grp == c) { d0r = zd; qqr = zq; }
        if (c < 7) { cA0 = nA0; cA1 = nA1; cB0 = nB0; cB1 = nB1; }
    }

    // phase 3: all 64 bins' scalar math lane-parallel (lane = bin)
    float wl = widths[lane];
    float tt = wl * fmaf(wl, qqr, 2.f * d0r);     // n2 increment of bin `lane`
    float incl = incl_scan(tt);
    float n2L = fmaxf(n2_0 + (incl - tt), 0.f);   // left-boundary norm^2
    float n2R = fmaxf(n2_0 + incl, 0.f);          // right-boundary norm^2
    float rrR = __builtin_amdgcn_sqrtf(n2R);
    float numerR = rrR * __expf(bsum - rrR);
    // numerL = numerR of lane-1 via DPP wave_shr:1 (lane 0 patched below)
    float numerL = __int_as_float(
        __builtin_amdgcn_update_dpp(0, __float_as_int(numerR), 0x138, 0xF, 0xF, true));
    numerL = (lane == 0) ? numer0 : numerL;
    float pd = fmaf(wl, qqr, d0r);                // dot1 = d0 + w*qq
    float term = numerR * __builtin_amdgcn_rcpf(pd + EPSF)
               - numerL * __builtin_amdgcn_rcpf(d0r + EPSF);
    float acc = reduce1(term);

    table[(size_t)p * BB + lane] = make_float4(n2L, d0r, qqr, bsum);

    if (lane == 0) bacc[wid] = (double)acc;
    __syncthreads();
    if (threadIdx.x == 0)
        atomicAdd(acc_out, bacc[0] + bacc[1] + bacc[2] + bacc[3]);
}

__global__ __launch_bounds__(256) void k_events(
    const float* __restrict__ times, const int* __restrict__ epid,
    const float* __restrict__ bounds, const float* __restrict__ innerPad,
    const float4* __restrict__ table, double* __restrict__ acc_out) {
    __shared__ float si[64];
    __shared__ float sb[BB + 1];
    __shared__ double wacc[4];
    int tid = threadIdx.x;
    if (tid < 64) si[tid] = innerPad[tid];
    if (tid <= BB) sb[tid] = bounds[tid];
    __syncthreads();
    int g = (blockIdx.x * 256 + tid) * 4;          // 4 events per thread
    float4 tm4 = *(const float4*)(times + g);
    int4 pd4 = *(const int4*)(epid + g);
    float tms[4] = {tm4.x, tm4.y, tm4.z, tm4.w};
    int pids[4] = {pd4.x, pd4.y, pd4.z, pd4.w};
    int cc[4];
    float rem[4];
#pragma unroll
    for (int k = 0; k < 4; k++) {
        int c = 0;  // searchsorted(inner, tm, 'right') via binary search over padded 64
        float tm = tms[k];
#pragma unroll
        for (int s = 32; s >= 1; s >>= 1)
            if (si[c + s - 1] <= tm) c += s;
        cc[k] = c;
        rem[k] = tm - sb[c];
    }
    // 4 independent gathers in flight together
    float4 e0 = table[(size_t)pids[0] * BB + cc[0]];
    float4 e1 = table[(size_t)pids[1] * BB + cc[1]];
    float4 e2 = table[(size_t)pids[2] * BB + cc[2]];
    float4 e3 = table[(size_t)pids[3] * BB + cc[3]];
    float eacc = 0.f;
    {
        float d2 = fmaxf(fmaf(rem[0], fmaf(rem[0], e0.z, 2.f * e0.y), e0.x), 0.f);
        eacc += e0.w - __builtin_amdgcn_sqrtf(d2);
        d2 = fmaxf(fmaf(rem[1], fmaf(rem[1], e1.z, 2.f * e1.y), e1.x), 0.f);
        eacc += e1.w - __builtin_amdgcn_sqrtf(d2);
        d2 = fmaxf(fmaf(rem[2], fmaf(rem[2], e2.z, 2.f * e2.y), e2.x), 0.f);
        eacc += e2.w - __builtin_amdgcn_sqrtf(d2);
        d2 = fmaxf(fmaf(rem[3], fmaf(rem[3], e3.z, 2.f * e3.y), e3.x), 0.f);
        eacc += e3.w - __builtin_amdgcn_sqrtf(d2);
    }
    float val = reduce1(eacc);
    if ((tid & 63) == 0) wacc[tid >> 6] = (double)val;
    __syncthreads();
    if (tid == 0)
        atomicAdd(acc_out, -(wacc[0] + wacc[1] + wacc[2] + wacc[3]));
}

__global__ void k_finalize(const double* __restrict__ acc, float* __restrict__ out) {
    out[0] = (float)(*acc);
}

extern "C" void kernel_launch(void* const* d_in, const int* in_sizes, int n_in,
                              void* d_out, int out_size, void* d_ws, size_t ws_size,
                              hipStream_t stream) {
    const float* x0     = (const float*)d_in[0];
    const float* v      = (const float*)d_in[1];
    const float* beta   = (const float*)d_in[2];
    const float* brw    = (const float*)d_in[3];
    const float* etimes = (const float*)d_in[4];
    const int*   pairs  = (const int*)d_in[5];
    const int*   epid   = (const int*)d_in[6];

    char* ws = (char*)d_ws;
    double* acc     = (double*)ws;
    int* cnt        = (int*)(ws + 1024);
    int* cursor     = (int*)(ws + 9216);
    int* perm       = (int*)(ws + 17408);
    float* bounds   = (float*)(ws + 82944);
    float* widths   = (float*)(ws + 83456);
    float* innerPad = (float*)(ws + 83968);
    float4* table   = (float4*)(ws + 84480);

    hipLaunchKernelGGL(k_bounds, dim3(9), dim3(64), 0, stream, brw, bounds, widths,
                       innerPad, cnt, acc);
    hipLaunchKernelGGL(k_hist2, dim3(PP / 256), dim3(256), 0, stream, pairs, cnt);
    hipLaunchKernelGGL(k_scan2, dim3(1), dim3(1024), 0, stream, cnt, cursor);
    hipLaunchKernelGGL(k_scatter2, dim3(PP / 256), dim3(256), 0, stream, pairs, cursor, perm);
    hipLaunchKernelGGL(k_pairs, dim3(PP / 4), dim3(256), 0, stream, x0, v, beta, pairs,
                       perm, widths, table, acc);
    hipLaunchKernelGGL(k_events, dim3(TT / 1024), dim3(256), 0, stream, etimes, epid,
                       bounds, innerPad, table, acc);
    hipLaunchKernelGGL(k_finalize, dim3(1), dim3(1), 0, stream, acc, (float*)d_out);
}